// Round 5
// baseline (218.946 us; speedup 1.0000x reference)
//
#include <hip/hip_runtime.h>

#define N_NODES 200000
#define SDIM 128
#define VDIM 128
#define NGRAPH 512
#define EPS 1e-6f
#define GPB 2                        // graphs per block
#define NBLK (NGRAPH / GPB)          // 256 blocks x 1024 threads

typedef float v4f __attribute__((ext_vector_type(4)));

// ---------------- Graph boundaries: starts[g] = lower_bound(index, g) ----------------
__global__ void eln_bounds(const int* __restrict__ index, int* __restrict__ starts) {
    for (int g = threadIdx.x; g <= NGRAPH; g += blockDim.x) {
        int lo = 0, hi = N_NODES;
        while (lo < hi) {
            int mid = (lo + hi) >> 1;
            if (index[mid] < g) lo = mid + 1; else hi = mid;
        }
        starts[g] = lo;
    }
}

// ---------------- Fused per-graph kernel: stats (phase 1) + outputs (phase 2) ----------
// Sorted index => graph g owns the contiguous node range [starts[g], starts[g+1]).
// One block handles 2 graphs sequentially. Phase-1 reads are cached; with 256
// concurrent blocks the in-flight working set is ~205 MB < 256 MB L3, so the
// phase-2 re-read hits L3. Outputs are nt stores (no cache pollution).
__global__ void __launch_bounds__(1024) eln_graph(const float* __restrict__ s,
                                                  const float* __restrict__ v,
                                                  const float* __restrict__ wgt,
                                                  const float* __restrict__ bias,
                                                  const int* __restrict__ starts,
                                                  float* __restrict__ out) {
    __shared__ float redA[16], redB[16], redC[16];
    __shared__ float sh_stats[3];

    const int tid  = threadIdx.x;
    const int lane = tid & 63;
    const int wv   = tid >> 6;

    const v4f* s4  = reinterpret_cast<const v4f*>(s);
    const v4f* v4p = reinterpret_cast<const v4f*>(v);
    const v4f* w4  = reinterpret_cast<const v4f*>(wgt);
    const v4f* b4  = reinterpret_cast<const v4f*>(bias);
    v4f* o4s = reinterpret_cast<v4f*>(out);
    v4f* o4v = reinterpret_cast<v4f*>(out + (size_t)N_NODES * SDIM);

    for (int k = 0; k < GPB; ++k) {
        const int g  = blockIdx.x * GPB + k;
        const int st = starts[g];
        const int c  = starts[g + 1] - st;
        if (c > 0) {                          // block-uniform -> syncs are safe
            const int nS = c * 32;            // float4s in s rows
            const int nV = c * 96;            // float4s in v rows
            const size_t baseS = (size_t)st * 32;
            const size_t baseV = (size_t)st * 96;

            // ---- phase 1: accumulate sum(s), sum(s^2), sum(v^2) ----
            float ssum = 0.f, s2 = 0.f, vs = 0.f;
#pragma unroll 4
            for (int i = tid; i < nS; i += 1024) {
                v4f a = s4[baseS + i];
                ssum += (a[0] + a[1]) + (a[2] + a[3]);
                s2 = fmaf(a[0], a[0], fmaf(a[1], a[1], fmaf(a[2], a[2], fmaf(a[3], a[3], s2))));
            }
#pragma unroll 4
            for (int i = tid; i < nV; i += 1024) {
                v4f b = v4p[baseV + i];
                vs = fmaf(b[0], b[0], fmaf(b[1], b[1], fmaf(b[2], b[2], fmaf(b[3], b[3], vs))));
            }
#pragma unroll
            for (int off = 32; off >= 1; off >>= 1) {
                ssum += __shfl_xor(ssum, off);
                s2   += __shfl_xor(s2, off);
                vs   += __shfl_xor(vs, off);
            }
            if (lane == 0) { redA[wv] = ssum; redB[wv] = s2; redC[wv] = vs; }
            __syncthreads();
            if (tid == 0) {
                float A = 0.f, B = 0.f, C = 0.f;
#pragma unroll
                for (int w = 0; w < 16; ++w) { A += redA[w]; B += redB[w]; C += redC[w]; }
                float inv   = 1.0f / (128.0f * (float)c);
                float smean = A * inv;
                float var   = fmaxf(B * inv - smean * smean, EPS);   // E[s^2]-E[s]^2
                float vmean = fmaxf(C * inv, EPS);
                sh_stats[0] = smean;
                sh_stats[1] = 1.0f / var;     // reference divides by var, not sqrt
                sh_stats[2] = 1.0f / vmean;
            }
            __syncthreads();
            const float smean = sh_stats[0], ivar = sh_stats[1], ivm = sh_stats[2];

            // ---- phase 2: outputs; reads hit L3 (just-read data), nt stores ----
#pragma unroll 2
            for (int i = tid; i < nS; i += 1024) {
                v4f a = s4[baseS + i];
                int d4 = i & 31;              // position within the 128-wide row
                v4f o = (a - smean) * ivar * w4[d4] + b4[d4];
                __builtin_nontemporal_store(o, o4s + baseS + i);
            }
#pragma unroll 2
            for (int i = tid; i < nV; i += 1024) {
                v4f b = v4p[baseV + i];
                __builtin_nontemporal_store(b * ivm, o4v + baseV + i);
            }
        }
        __syncthreads();                      // LDS reuse across k
    }
}

extern "C" void kernel_launch(void* const* d_in, const int* in_sizes, int n_in,
                              void* d_out, int out_size, void* d_ws, size_t ws_size,
                              hipStream_t stream) {
    const float* s      = (const float*)d_in[0];
    const float* v      = (const float*)d_in[1];
    const int*   index  = (const int*)d_in[2];
    const float* weight = (const float*)d_in[3];
    const float* bias   = (const float*)d_in[4];
    float* out  = (float*)d_out;
    int*   strt = (int*)d_ws;

    eln_bounds<<<1, 512, 0, stream>>>(index, strt);
    eln_graph<<<NBLK, 1024, 0, stream>>>(s, v, weight, bias, strt, out);
}

// Round 6
// 208.630 us; speedup vs baseline: 1.0494x; 1.0494x over previous
//
#include <hip/hip_runtime.h>

#define N_NODES 200000
#define SDIM 128
#define VDIM 128
#define NGRAPH 512
#define EPS 1e-6f

typedef float v4f __attribute__((ext_vector_type(4)));

// ---------------- Graph boundaries: starts[g] = lower_bound(index, g) ----------------
__global__ void eln_bounds(const int* __restrict__ index, int* __restrict__ starts) {
    for (int g = threadIdx.x; g <= NGRAPH; g += blockDim.x) {
        int lo = 0, hi = N_NODES;
        while (lo < hi) {
            int mid = (lo + hi) >> 1;
            if (index[mid] < g) lo = mid + 1; else hi = mid;
        }
        starts[g] = lo;
    }
}

// ---------------- Fused per-graph kernel: stats (phase 1) + outputs (phase 2) ----------
// One graph per block; 512 blocks x 1024 threads = 2 blocks/CU = 32 waves/CU
// (round-4 post-mortem: 1 block/CU was latency-bound at 19 GB/s/CU).
// Phase-1 reads cached (future reuse in phase 2); phase-2 reads are nt PROBES
// (dead after this touch -> don't occupy L3 MRU), stores nt.
__global__ void __launch_bounds__(1024) eln_graph(const float* __restrict__ s,
                                                  const float* __restrict__ v,
                                                  const float* __restrict__ wgt,
                                                  const float* __restrict__ bias,
                                                  const int* __restrict__ starts,
                                                  float* __restrict__ out) {
    __shared__ float redA[16], redB[16], redC[16];
    __shared__ float sh_stats[3];

    const int tid  = threadIdx.x;
    const int lane = tid & 63;
    const int wv   = tid >> 6;

    const int g  = blockIdx.x;
    const int st = starts[g];
    const int c  = starts[g + 1] - st;
    if (c == 0) return;                       // block-uniform

    const v4f* s4  = reinterpret_cast<const v4f*>(s);
    const v4f* v4p = reinterpret_cast<const v4f*>(v);
    const v4f* w4  = reinterpret_cast<const v4f*>(wgt);
    const v4f* b4  = reinterpret_cast<const v4f*>(bias);
    v4f* o4s = reinterpret_cast<v4f*>(out);
    v4f* o4v = reinterpret_cast<v4f*>(out + (size_t)N_NODES * SDIM);

    const int nS = c * 32;                    // float4s in s rows
    const int nV = c * 96;                    // float4s in v rows
    const size_t baseS = (size_t)st * 32;
    const size_t baseV = (size_t)st * 96;

    // ---- phase 1: accumulate sum(s), sum(s^2), sum(v^2); cached loads ----
    float ssum = 0.f, s2 = 0.f, vs = 0.f;
#pragma unroll 4
    for (int i = tid; i < nS; i += 1024) {
        v4f a = s4[baseS + i];
        ssum += (a[0] + a[1]) + (a[2] + a[3]);
        s2 = fmaf(a[0], a[0], fmaf(a[1], a[1], fmaf(a[2], a[2], fmaf(a[3], a[3], s2))));
    }
#pragma unroll 4
    for (int i = tid; i < nV; i += 1024) {
        v4f b = v4p[baseV + i];
        vs = fmaf(b[0], b[0], fmaf(b[1], b[1], fmaf(b[2], b[2], fmaf(b[3], b[3], vs))));
    }
#pragma unroll
    for (int off = 32; off >= 1; off >>= 1) {
        ssum += __shfl_xor(ssum, off);
        s2   += __shfl_xor(s2, off);
        vs   += __shfl_xor(vs, off);
    }
    if (lane == 0) { redA[wv] = ssum; redB[wv] = s2; redC[wv] = vs; }
    __syncthreads();
    if (tid == 0) {
        float A = 0.f, B = 0.f, C = 0.f;
#pragma unroll
        for (int w = 0; w < 16; ++w) { A += redA[w]; B += redB[w]; C += redC[w]; }
        float inv   = 1.0f / (128.0f * (float)c);
        float smean = A * inv;
        float var   = fmaxf(B * inv - smean * smean, EPS);   // E[s^2]-E[s]^2
        float vmean = fmaxf(C * inv, EPS);
        sh_stats[0] = smean;
        sh_stats[1] = 1.0f / var;             // reference divides by var, not sqrt
        sh_stats[2] = 1.0f / vmean;
    }
    __syncthreads();
    const float smean = sh_stats[0], ivar = sh_stats[1], ivm = sh_stats[2];

    // ---- phase 2: outputs; nt probe loads (last touch), nt stores ----
#pragma unroll 2
    for (int i = tid; i < nS; i += 1024) {
        v4f a = __builtin_nontemporal_load(s4 + baseS + i);
        int d4 = i & 31;                      // position within the 128-wide row
        v4f o = (a - smean) * ivar * w4[d4] + b4[d4];
        __builtin_nontemporal_store(o, o4s + baseS + i);
    }
#pragma unroll 2
    for (int i = tid; i < nV; i += 1024) {
        v4f b = __builtin_nontemporal_load(v4p + baseV + i);
        __builtin_nontemporal_store(b * ivm, o4v + baseV + i);
    }
}

extern "C" void kernel_launch(void* const* d_in, const int* in_sizes, int n_in,
                              void* d_out, int out_size, void* d_ws, size_t ws_size,
                              hipStream_t stream) {
    const float* s      = (const float*)d_in[0];
    const float* v      = (const float*)d_in[1];
    const int*   index  = (const int*)d_in[2];
    const float* weight = (const float*)d_in[3];
    const float* bias   = (const float*)d_in[4];
    float* out  = (float*)d_out;
    int*   strt = (int*)d_ws;

    eln_bounds<<<1, 512, 0, stream>>>(index, strt);
    eln_graph<<<NGRAPH, 1024, 0, stream>>>(s, v, weight, bias, strt, out);
}